// Round 2
// baseline (440.647 us; speedup 1.0000x reference)
//
#include <hip/hip_runtime.h>
#include <hip/hip_bf16.h>
#include <stdint.h>

// Problem constants
#define CH     256
#define NSP    9216
#define NBATCH 8
#define NSPLIT 8
#define KSEG   1152  // NSP / NSPLIT

typedef unsigned short ushort_t;
using f32x4  = __attribute__((ext_vector_type(4))) float;
using bf16x8 = __attribute__((ext_vector_type(8))) short;

__device__ __forceinline__ ushort_t f2b(float f) {
  union { float f; uint32_t u; } v; v.f = f;
  return (ushort_t)((v.u + 0x7FFFu + ((v.u >> 16) & 1u)) >> 16);
}

// XOR swizzle for 128-byte LDS rows: spreads 16-lane row-strided b128 reads
// across banks (guide G4). Must be applied identically on write and read.
__device__ __forceinline__ uint32_t swz(uint32_t row, uint32_t byte) {
  return row * 128u + (byte ^ ((row & 7u) << 4));
}

// ---------------------------------------------------------------------------
// K0: convert the five 256x256 fp32 weight matrices to bf16 (contiguous dst)
// ---------------------------------------------------------------------------
__global__ void wconv_kernel(const float* __restrict__ w0, const float* __restrict__ w1,
                             const float* __restrict__ w2, const float* __restrict__ w3,
                             const float* __restrict__ w4, ushort_t* __restrict__ dst) {
  int i = blockIdx.x * 256 + threadIdx.x;   // 5*65536 total
  int sel = i >> 16;
  int loc = i & 0xFFFF;
  const float* s = (sel == 0) ? w0 : (sel == 1) ? w1 : (sel == 2) ? w2 : (sel == 3) ? w3 : w4;
  dst[i] = f2b(s[loc]);
}

// ---------------------------------------------------------------------------
// Generic channel-mix GEMM:  dst[b,co,n] = sum_ci A[co,ci] * src[b,ci,n] + bias
// A: bf16 [256][256] (pre-converted weights). src: fp32 or bf16 [B][256][NSP].
// Block: 256 thr (4 waves), tile M=256 x N=64, K-chunks of 64.
// NOUT=2 computes two projections from the same src (shares the B operand).
// ---------------------------------------------------------------------------
template<int NOUT, bool IN_F32, bool LRELU, bool OUT_F32>
__global__ __launch_bounds__(256)
void conv_gemm_kernel(const ushort_t* __restrict__ A0, const float* __restrict__ bias0,
                      void* __restrict__ dst0,
                      const ushort_t* __restrict__ A1, const float* __restrict__ bias1,
                      ushort_t* __restrict__ dst1,
                      const void* __restrict__ srcv) {
  const int b    = blockIdx.y;
  const int n0   = blockIdx.x * 64;
  const int tid  = threadIdx.x;
  const int lane = tid & 63;
  const int w    = tid >> 6;

  __shared__ __align__(16) unsigned char sA0[256 * 128];
  __shared__ __align__(16) unsigned char sA1[(NOUT == 2) ? 256 * 128 : 16];
  __shared__ __align__(16) unsigned char sB[64 * 128];

  f32x4 acc0[4][4];
  f32x4 acc1[4][4];
  #pragma unroll
  for (int i = 0; i < 4; ++i)
    #pragma unroll
    for (int j = 0; j < 4; ++j)
      #pragma unroll
      for (int r = 0; r < 4; ++r) { acc0[i][j][r] = 0.f; acc1[i][j][r] = 0.f; }

  for (int kc = 0; kc < 4; ++kc) {
    const int k0 = kc * 64;
    // ---- stage A chunk(s): [256 co][64 k] bf16, k-contiguous rows ----
    #pragma unroll
    for (int it = 0; it < 8; ++it) {
      int slot = it * 256 + tid;
      int row  = slot >> 3;
      int seg  = slot & 7;
      uint4 d0 = *reinterpret_cast<const uint4*>(A0 + row * CH + k0 + seg * 8);
      *reinterpret_cast<uint4*>(&sA0[swz(row, seg * 16)]) = d0;
      if constexpr (NOUT == 2) {
        uint4 d1 = *reinterpret_cast<const uint4*>(A1 + row * CH + k0 + seg * 8);
        *reinterpret_cast<uint4*>(&sA1[swz(row, seg * 16)]) = d1;
      }
    }
    // ---- stage B chunk transposed: LDS layout [n][k] so fragments are
    //      8 consecutive k per lane (ds_read_b128) ----
    if constexpr (IN_F32) {
      const float* src = (const float*)srcv;
      #pragma unroll
      for (int r = 0; r < 4; ++r) {
        int ci = (tid >> 4) + r * 16;
        int nl = (tid & 15) * 4;
        float4 vv = *reinterpret_cast<const float4*>(
            src + ((size_t)b * CH + (k0 + ci)) * NSP + n0 + nl);
        float fv[4] = {vv.x, vv.y, vv.z, vv.w};
        #pragma unroll
        for (int j = 0; j < 4; ++j) {
          int jj = (j + (tid & 3)) & 3;   // lane-stagger to spread write banks
          *reinterpret_cast<ushort_t*>(&sB[swz(nl + jj, ci * 2)]) = f2b(fv[jj]);
        }
      }
    } else {
      const ushort_t* src = (const ushort_t*)srcv;
      #pragma unroll
      for (int r = 0; r < 2; ++r) {
        int ci = (tid >> 3) + r * 32;
        int nl = (tid & 7) * 8;
        uint4 dv = *reinterpret_cast<const uint4*>(
            src + ((size_t)b * CH + (k0 + ci)) * NSP + n0 + nl);
        const ushort_t* hv = reinterpret_cast<const ushort_t*>(&dv);
        #pragma unroll
        for (int j = 0; j < 8; ++j) {
          int jj = (j + (tid & 7)) & 7;
          *reinterpret_cast<ushort_t*>(&sB[swz(nl + jj, ci * 2)]) = hv[jj];
        }
      }
    }
    __syncthreads();
    // ---- MFMA: two K=32 steps per chunk ----
    #pragma unroll
    for (int ks = 0; ks < 2; ++ks) {
      const int kb = ks * 64 + (lane >> 4) * 16;
      bf16x8 fb[4], fa0[4];
      #pragma unroll
      for (int ni = 0; ni < 4; ++ni)
        fb[ni] = *reinterpret_cast<const bf16x8*>(&sB[swz(ni * 16 + (lane & 15), kb)]);
      #pragma unroll
      for (int mi = 0; mi < 4; ++mi)
        fa0[mi] = *reinterpret_cast<const bf16x8*>(&sA0[swz(w * 64 + mi * 16 + (lane & 15), kb)]);
      #pragma unroll
      for (int mi = 0; mi < 4; ++mi)
        #pragma unroll
        for (int ni = 0; ni < 4; ++ni)
          acc0[mi][ni] = __builtin_amdgcn_mfma_f32_16x16x32_bf16(fa0[mi], fb[ni], acc0[mi][ni], 0, 0, 0);
      if constexpr (NOUT == 2) {
        bf16x8 fa1[4];
        #pragma unroll
        for (int mi = 0; mi < 4; ++mi)
          fa1[mi] = *reinterpret_cast<const bf16x8*>(&sA1[swz(w * 64 + mi * 16 + (lane & 15), kb)]);
        #pragma unroll
        for (int mi = 0; mi < 4; ++mi)
          #pragma unroll
          for (int ni = 0; ni < 4; ++ni)
            acc1[mi][ni] = __builtin_amdgcn_mfma_f32_16x16x32_bf16(fa1[mi], fb[ni], acc1[mi][ni], 0, 0, 0);
      }
    }
    __syncthreads();
  }
  // ---- epilogue: bias (+optional LeakyReLU), store [b][co][n] ----
  #pragma unroll
  for (int mi = 0; mi < 4; ++mi) {
    const int coB = w * 64 + mi * 16 + ((lane >> 4) << 2);
    #pragma unroll
    for (int ni = 0; ni < 4; ++ni) {
      const int n = n0 + ni * 16 + (lane & 15);
      #pragma unroll
      for (int r = 0; r < 4; ++r) {
        const int co = coB + r;
        const size_t oidx = ((size_t)b * CH + co) * NSP + n;
        float x = acc0[mi][ni][r] + bias0[co];
        if constexpr (LRELU) x = (x >= 0.f) ? x : 0.01f * x;
        if constexpr (OUT_F32) ((float*)dst0)[oidx] = x;
        else                   ((ushort_t*)dst0)[oidx] = f2b(x);
        if constexpr (NOUT == 2) {
          float y = acc1[mi][ni][r] + bias1[co];
          dst1[oidx] = f2b(y);
        }
      }
    }
  }
}

// ---------------------------------------------------------------------------
// K2: split-K score partials. part[b,s,c,d] = sum_{k in seg s} qry[b,c,k]*key[b,d,k]
// Block tile 128x128, 4 waves (2x2 of 64x64). K per block = KSEG (chunks of 64).
// Both operands are k-contiguous in global — no transpose staging needed.
// NSPLIT=8 -> 256 blocks = one per CU; deterministic reduction in softmax.
// ---------------------------------------------------------------------------
__global__ __launch_bounds__(256)
void scores_kernel(const ushort_t* __restrict__ qry, const ushort_t* __restrict__ key,
                   float* __restrict__ part) {
  const int b  = blockIdx.z;
  const int s  = blockIdx.y;
  const int c0 = (blockIdx.x >> 1) * 128;
  const int d0 = (blockIdx.x & 1) * 128;
  const int tid  = threadIdx.x;
  const int lane = tid & 63;
  const int wm = (tid >> 7) & 1;
  const int wn = (tid >> 6) & 1;

  __shared__ __align__(16) unsigned char sQ[128 * 128];
  __shared__ __align__(16) unsigned char sK[128 * 128];

  f32x4 acc[4][4];
  #pragma unroll
  for (int i = 0; i < 4; ++i)
    #pragma unroll
    for (int j = 0; j < 4; ++j)
      #pragma unroll
      for (int r = 0; r < 4; ++r) acc[i][j][r] = 0.f;

  for (int kc = 0; kc < KSEG / 64; ++kc) {
    const int k0 = s * KSEG + kc * 64;
    #pragma unroll
    for (int it = 0; it < 4; ++it) {
      int slot = it * 256 + tid;
      int row  = slot >> 3;
      int seg  = slot & 7;
      *reinterpret_cast<uint4*>(&sQ[swz(row, seg * 16)]) =
          *reinterpret_cast<const uint4*>(qry + ((size_t)b * CH + c0 + row) * NSP + k0 + seg * 8);
      *reinterpret_cast<uint4*>(&sK[swz(row, seg * 16)]) =
          *reinterpret_cast<const uint4*>(key + ((size_t)b * CH + d0 + row) * NSP + k0 + seg * 8);
    }
    __syncthreads();
    #pragma unroll
    for (int ks = 0; ks < 2; ++ks) {
      const int kb = ks * 64 + (lane >> 4) * 16;
      bf16x8 fq[4], fk[4];
      #pragma unroll
      for (int mi = 0; mi < 4; ++mi)
        fq[mi] = *reinterpret_cast<const bf16x8*>(&sQ[swz(wm * 64 + mi * 16 + (lane & 15), kb)]);
      #pragma unroll
      for (int ni = 0; ni < 4; ++ni)
        fk[ni] = *reinterpret_cast<const bf16x8*>(&sK[swz(wn * 64 + ni * 16 + (lane & 15), kb)]);
      #pragma unroll
      for (int mi = 0; mi < 4; ++mi)
        #pragma unroll
        for (int ni = 0; ni < 4; ++ni)
          acc[mi][ni] = __builtin_amdgcn_mfma_f32_16x16x32_bf16(fq[mi], fk[ni], acc[mi][ni], 0, 0, 0);
    }
    __syncthreads();
  }
  const size_t base = ((size_t)b * NSPLIT + s) * CH;
  #pragma unroll
  for (int mi = 0; mi < 4; ++mi) {
    #pragma unroll
    for (int ni = 0; ni < 4; ++ni) {
      #pragma unroll
      for (int r = 0; r < 4; ++r) {
        int c = c0 + wm * 64 + mi * 16 + ((lane >> 4) << 2) + r;
        int d = d0 + wn * 64 + ni * 16 + (lane & 15);
        part[(base + c) * CH + d] = acc[mi][ni][r];
      }
    }
  }
}

// ---------------------------------------------------------------------------
// K3: reduce partials + softmax over d -> attn bf16. One wave per (b, c-row).
// ---------------------------------------------------------------------------
__global__ __launch_bounds__(64)
void softmax_kernel(const float* __restrict__ part, ushort_t* __restrict__ attn) {
  const int c = blockIdx.x;
  const int b = blockIdx.y;
  const int lane = threadIdx.x;
  float sv[4] = {0.f, 0.f, 0.f, 0.f};
  for (int sp = 0; sp < NSPLIT; ++sp) {
    const float* p = part + (((size_t)b * NSPLIT + sp) * CH + c) * CH;
    #pragma unroll
    for (int r = 0; r < 4; ++r) sv[r] += p[r * 64 + lane];
  }
  #pragma unroll
  for (int r = 0; r < 4; ++r) sv[r] *= (1.0f / 96.0f);   // /= sqrt(9216)
  float m = fmaxf(fmaxf(sv[0], sv[1]), fmaxf(sv[2], sv[3]));
  for (int off = 32; off > 0; off >>= 1) m = fmaxf(m, __shfl_xor(m, off));
  float e[4]; float sum = 0.f;
  #pragma unroll
  for (int r = 0; r < 4; ++r) { e[r] = expf(sv[r] - m); sum += e[r]; }
  for (int off = 32; off > 0; off >>= 1) sum += __shfl_xor(sum, off);
  float inv = 1.0f / sum;
  ushort_t* ap = attn + ((size_t)b * CH + c) * CH;
  #pragma unroll
  for (int r = 0; r < 4; ++r) ap[r * 64 + lane] = f2b(e[r] * inv);
}

// ---------------------------------------------------------------------------
// K4: out[b,c,n] = sum_d attn[b,c,d] * val[b,d,n], then the faithful
// permute/view remap  t[b, n/36, (n%36)*256 + c] = lrelu(BN(out[b,c,n]))
// with BN channel = n/36 (exact: 9216 = 36*256). LDS-transpose epilogue ->
// 128B-contiguous global writes.
// ---------------------------------------------------------------------------
__global__ __launch_bounds__(256)
void attnout_kernel(const ushort_t* __restrict__ attn, const ushort_t* __restrict__ val,
                    const float* __restrict__ gamma, const float* __restrict__ beta,
                    const float* __restrict__ mean, const float* __restrict__ var,
                    ushort_t* __restrict__ tbuf) {
  const int b    = blockIdx.y;
  const int n0   = blockIdx.x * 64;
  const int tid  = threadIdx.x;
  const int lane = tid & 63;
  const int w    = tid >> 6;

  __shared__ __align__(16) unsigned char sm[64 * 260 * 4];  // 66560 B (staging + epilogue union)
  unsigned char* sA = sm;           // 32768 B: attn chunk [256 c][64 d]
  unsigned char* sB = sm + 32768;   //  8192 B: val chunk transposed [64 n][64 d]

  f32x4 acc[4][4];
  #pragma unroll
  for (int i = 0; i < 4; ++i)
    #pragma unroll
    for (int j = 0; j < 4; ++j)
      #pragma unroll
      for (int r = 0; r < 4; ++r) acc[i][j][r] = 0.f;

  for (int kc = 0; kc < 4; ++kc) {
    const int k0 = kc * 64;
    #pragma unroll
    for (int it = 0; it < 8; ++it) {
      int slot = it * 256 + tid;
      int row  = slot >> 3;
      int seg  = slot & 7;
      *reinterpret_cast<uint4*>(&sA[swz(row, seg * 16)]) =
          *reinterpret_cast<const uint4*>(attn + ((size_t)b * CH + row) * CH + k0 + seg * 8);
    }
    #pragma unroll
    for (int r = 0; r < 2; ++r) {
      int dl = (tid >> 3) + r * 32;
      int nl = (tid & 7) * 8;
      uint4 dv = *reinterpret_cast<const uint4*>(
          val + ((size_t)b * CH + (k0 + dl)) * NSP + n0 + nl);
      const ushort_t* hv = reinterpret_cast<const ushort_t*>(&dv);
      #pragma unroll
      for (int j = 0; j < 8; ++j) {
        int jj = (j + (tid & 7)) & 7;
        *reinterpret_cast<ushort_t*>(&sB[swz(nl + jj, dl * 2)]) = hv[jj];
      }
    }
    __syncthreads();
    #pragma unroll
    for (int ks = 0; ks < 2; ++ks) {
      const int kb = ks * 64 + (lane >> 4) * 16;
      bf16x8 fb[4], fa[4];
      #pragma unroll
      for (int ni = 0; ni < 4; ++ni)
        fb[ni] = *reinterpret_cast<const bf16x8*>(&sB[swz(ni * 16 + (lane & 15), kb)]);
      #pragma unroll
      for (int mi = 0; mi < 4; ++mi)
        fa[mi] = *reinterpret_cast<const bf16x8*>(&sA[swz(w * 64 + mi * 16 + (lane & 15), kb)]);
      #pragma unroll
      for (int mi = 0; mi < 4; ++mi)
        #pragma unroll
        for (int ni = 0; ni < 4; ++ni)
          acc[mi][ni] = __builtin_amdgcn_mfma_f32_16x16x32_bf16(fa[mi], fb[ni], acc[mi][ni], 0, 0, 0);
    }
    __syncthreads();
  }
  // transpose accumulators into eL[n][c] (stride 260 floats = 1040 B: float4-
  // aligned, and 260 mod 32 banks = 4 -> read conflicts bounded ~8-way)
  float* eL = reinterpret_cast<float*>(sm);
  #pragma unroll
  for (int mi = 0; mi < 4; ++mi) {
    #pragma unroll
    for (int ni = 0; ni < 4; ++ni) {
      #pragma unroll
      for (int r = 0; r < 4; ++r) {
        int c  = w * 64 + mi * 16 + ((lane >> 4) << 2) + r;
        int nl = ni * 16 + (lane & 15);
        eL[nl * 260 + c] = acc[mi][ni][r];
      }
    }
  }
  __syncthreads();
  const int ml = tid & 63;          // spatial within tile
  const int c0 = (tid >> 6) * 64;   // channel quarter
  const int m  = n0 + ml;
  const int cp = m / 36;
  const int npb = (m % 36) * 256 + c0;
  const float kf = gamma[cp] * rsqrtf(var[cp] + 1e-4f);
  const float bb = beta[cp] - mean[cp] * kf;
  ushort_t* op = tbuf + ((size_t)b * CH + cp) * NSP + npb;
  #pragma unroll
  for (int j = 0; j < 64; j += 4) {
    float4 xv = *reinterpret_cast<const float4*>(&eL[ml * 260 + c0 + j]);
    float x[4] = {xv.x, xv.y, xv.z, xv.w};
    #pragma unroll
    for (int t = 0; t < 4; ++t) {
      x[t] = x[t] * kf + bb;
      x[t] = (x[t] >= 0.f) ? x[t] : 0.01f * x[t];
    }
    uint2 pk;
    pk.x = (uint32_t)f2b(x[0]) | ((uint32_t)f2b(x[1]) << 16);
    pk.y = (uint32_t)f2b(x[2]) | ((uint32_t)f2b(x[3]) << 16);
    *reinterpret_cast<uint2*>(op + j) = pk;
  }
}

// ---------------------------------------------------------------------------
// Launch. Workspace layout (needs ~53.6 MB):
//   [0)         5 x 128KB bf16 weights (Wq,Wk,Wv,Wo1,Wo2)
//   [655360)    val bf16 (37748736 B)          -> reused as o1 after K4
//   [38404096)  score partials fp32 (16777216) (dead after softmax)
//   [55181312)  attn bf16 (1048576)
// d_out doubles as scratch (dead until the final conv writes it):
//   qry bf16 = d_out[0:37748736), key bf16 = d_out[37748736:75497472)
//   tbuf bf16 = d_out[0:37748736)  (qry dead after scores)
// ---------------------------------------------------------------------------
extern "C" void kernel_launch(void* const* d_in, const int* in_sizes, int n_in,
                              void* d_out, int out_size, void* d_ws, size_t ws_size,
                              hipStream_t stream) {
  (void)in_sizes; (void)n_in; (void)out_size; (void)ws_size;
  const float* q   = (const float*)d_in[0];
  const float* v   = (const float*)d_in[1];
  const float* Wq  = (const float*)d_in[2];
  const float* bq  = (const float*)d_in[3];
  const float* Wk  = (const float*)d_in[4];
  const float* bk  = (const float*)d_in[5];
  const float* Wv  = (const float*)d_in[6];
  const float* bv  = (const float*)d_in[7];
  const float* bng = (const float*)d_in[8];
  const float* bnb = (const float*)d_in[9];
  const float* bnm = (const float*)d_in[10];
  const float* bnv = (const float*)d_in[11];
  const float* Wo1 = (const float*)d_in[12];
  const float* bo1 = (const float*)d_in[13];
  const float* Wo2 = (const float*)d_in[14];
  const float* bo2 = (const float*)d_in[15];

  char* ws = (char*)d_ws;
  ushort_t* wq_b  = (ushort_t*)(ws);
  ushort_t* wk_b  = (ushort_t*)(ws + 131072);
  ushort_t* wv_b  = (ushort_t*)(ws + 262144);
  ushort_t* wo1_b = (ushort_t*)(ws + 393216);
  ushort_t* wo2_b = (ushort_t*)(ws + 524288);
  ushort_t* val   = (ushort_t*)(ws + 655360);
  float*    part  = (float*)   (ws + 655360 + 37748736);
  ushort_t* attn  = (ushort_t*)(ws + 655360 + 37748736 + 16777216);
  ushort_t* o1    = val;               // reuse: val dead after attnout
  ushort_t* qry   = (ushort_t*)d_out;  // d_out as scratch (dead before final write)
  ushort_t* key   = qry + 18874368;
  ushort_t* tbuf  = qry;               // reuse: qry dead after scores

  wconv_kernel<<<1280, 256, 0, stream>>>(Wq, Wk, Wv, Wo1, Wo2, wq_b);

  dim3 g1(NSP / 64, NBATCH);
  // q -> query (Wq) and value (Wv) in one pass over q
  conv_gemm_kernel<2, true, false, false><<<g1, 256, 0, stream>>>(
      wq_b, bq, (void*)qry, wv_b, bv, val, q);
  // v -> key (Wk)
  conv_gemm_kernel<1, true, false, false><<<g1, 256, 0, stream>>>(
      wk_b, bk, (void*)key, nullptr, nullptr, nullptr, v);

  scores_kernel<<<dim3(4, NSPLIT, NBATCH), 256, 0, stream>>>(qry, key, part);
  softmax_kernel<<<dim3(CH, NBATCH), 64, 0, stream>>>(part, attn);

  attnout_kernel<<<g1, 256, 0, stream>>>(attn, val, bng, bnb, bnm, bnv, tbuf);

  // conv_out: conv1 + LeakyReLU (bf16), then conv2 -> fp32 d_out
  conv_gemm_kernel<1, false, true, false><<<g1, 256, 0, stream>>>(
      wo1_b, bo1, (void*)o1, nullptr, nullptr, nullptr, tbuf);
  conv_gemm_kernel<1, false, false, true><<<g1, 256, 0, stream>>>(
      wo2_b, bo2, d_out, nullptr, nullptr, nullptr, o1);
}

// Round 5
// 403.155 us; speedup vs baseline: 1.0930x; 1.0930x over previous
//
#include <hip/hip_runtime.h>
#include <hip/hip_bf16.h>
#include <stdint.h>

// Problem constants
#define CH     256
#define NSP    9216
#define NBATCH 8
#define NSPLIT 8
#define KSEG   1152  // NSP / NSPLIT

typedef unsigned short ushort_t;
using f32x4  = __attribute__((ext_vector_type(4))) float;
using bf16x8 = __attribute__((ext_vector_type(8))) short;

__device__ __forceinline__ ushort_t f2b(float f) {
  union { float f; uint32_t u; } v; v.f = f;
  return (ushort_t)((v.u + 0x7FFFu + ((v.u >> 16) & 1u)) >> 16);
}

// XOR swizzle for 128-byte LDS rows (key = row&7, moves 16B slots).
__device__ __forceinline__ uint32_t swz(uint32_t row, uint32_t byte) {
  return row * 128u + (byte ^ ((row & 7u) << 4));
}

// global -> LDS async DMA, 16B per lane. lds base must be wave-uniform;
// global address is per-lane.
typedef __attribute__((address_space(3))) void       lds_void;
typedef const __attribute__((address_space(1))) void g_void;
__device__ __forceinline__ void glds16(const void* g, void* l) {
  __builtin_amdgcn_global_load_lds((g_void*)g, (lds_void*)l, 16, 0, 0);
}

// ---------------------------------------------------------------------------
// K0: convert 5 fp32 256x256 weights into chunk-swizzled bf16 images.
// Image layout per matrix: [kc in 4][co in 256][128B row], row bytes stored at
// (bt ^ ((co&7)<<4)) so the image IS the LDS tile -> global_load_lds linear.
// ---------------------------------------------------------------------------
__global__ void wconv_kernel(const float* __restrict__ w0, const float* __restrict__ w1,
                             const float* __restrict__ w2, const float* __restrict__ w3,
                             const float* __restrict__ w4, ushort_t* __restrict__ dst) {
  int gid = blockIdx.x * 256 + threadIdx.x;   // 40960 16B-units total
  int m   = gid >> 13;                        // matrix id (8192 units each)
  int u   = gid & 8191;
  const float* W = (m == 0) ? w0 : (m == 1) ? w1 : (m == 2) ? w2 : (m == 3) ? w3 : w4;
  int lin = u * 16;                           // byte offset within 128KB image
  int kc  = lin >> 15;
  int co  = (lin >> 7) & 255;
  int bb0 = lin & 127;                        // 16B-aligned
  int k0  = kc * 64 + ((bb0 ^ ((co & 7) << 4)) >> 1);   // 8-elem aligned
  const float* srow = W + co * 256 + k0;
  float4 a = *reinterpret_cast<const float4*>(srow);
  float4 c = *reinterpret_cast<const float4*>(srow + 4);
  ushort_t o[8] = {f2b(a.x), f2b(a.y), f2b(a.z), f2b(a.w),
                   f2b(c.x), f2b(c.y), f2b(c.z), f2b(c.w)};
  uint4 pk;
  pk.x = (uint32_t)o[0] | ((uint32_t)o[1] << 16);
  pk.y = (uint32_t)o[2] | ((uint32_t)o[3] << 16);
  pk.z = (uint32_t)o[4] | ((uint32_t)o[5] << 16);
  pk.w = (uint32_t)o[6] | ((uint32_t)o[7] << 16);
  *reinterpret_cast<uint4*>(dst + m * 65536 + (lin >> 1)) = pk;
}

// ---------------------------------------------------------------------------
// K1: projection GEMM dst[b,co,n] = sum_ci A[co,ci]*src[b,ci,n] + bias.
// A from pre-swizzled image via global_load_lds. src fp32. Tile 256co x 64n.
// NOUT=2: second output (value) is written TRANSPOSED+swizzled: val_t[n][d]
// rows of 512B with 16B slots XORed by (n&7)<<4 (so MEGA can re-key cheaply).
// ---------------------------------------------------------------------------
template<int NOUT>
__global__ __launch_bounds__(256)
void proj_kernel(const ushort_t* __restrict__ Asw0, const float* __restrict__ bias0,
                 ushort_t* __restrict__ dst0,
                 const ushort_t* __restrict__ Asw1, const float* __restrict__ bias1,
                 char* __restrict__ valt,
                 const float* __restrict__ src) {
  const int b    = blockIdx.y;
  const int n0   = blockIdx.x * 64;
  const int tid  = threadIdx.x;
  const int lane = tid & 63;
  const int w    = tid >> 6;

  __shared__ __align__(16) unsigned char sA0[32768];
  __shared__ __align__(16) unsigned char sA1[(NOUT == 2) ? 32768 : 16];
  __shared__ __align__(16) unsigned char sB[8192];

  f32x4 acc0[4][4];
  f32x4 acc1[4][4];
  #pragma unroll
  for (int i = 0; i < 4; ++i)
    #pragma unroll
    for (int j = 0; j < 4; ++j)
      #pragma unroll
      for (int r = 0; r < 4; ++r) { acc0[i][j][r] = 0.f; acc1[i][j][r] = 0.f; }

  for (int kc = 0; kc < 4; ++kc) {
    const int k0 = kc * 64;
    if (kc > 0) __syncthreads();          // protect LDS from previous readers
    // ---- A chunks via global_load_lds (linear copy of pre-swizzled image) --
    #pragma unroll
    for (int it = 0; it < 8; ++it) {
      int seg = (it * 4 + w) * 1024;      // wave-uniform 1KB segment
      glds16((const char*)Asw0 + kc * 32768 + seg + lane * 16,
             (void*)(sA0 + seg));
      if constexpr (NOUT == 2)
        glds16((const char*)Asw1 + kc * 32768 + seg + lane * 16,
               (void*)(sA1 + seg));
    }
    // ---- B chunk: fp32 [ci][n] -> bf16 LDS [n][ci] swizzled, packed b64 ----
    {
      const int ci0 = (tid >> 4) * 4;     // 4 consecutive ci
      const int n4  = (tid & 15) * 4;     // 4 consecutive n
      float xv[4][4];
      #pragma unroll
      for (int r = 0; r < 4; ++r) {
        float4 t4 = *reinterpret_cast<const float4*>(
            src + ((size_t)b * CH + (k0 + ci0 + r)) * NSP + n0 + n4);
        xv[r][0] = t4.x; xv[r][1] = t4.y; xv[r][2] = t4.z; xv[r][3] = t4.w;
      }
      #pragma unroll
      for (int j = 0; j < 4; ++j) {
        uint64_t pk = (uint64_t)f2b(xv[0][j])
                    | ((uint64_t)f2b(xv[1][j]) << 16)
                    | ((uint64_t)f2b(xv[2][j]) << 32)
                    | ((uint64_t)f2b(xv[3][j]) << 48);
        *reinterpret_cast<uint64_t*>(&sB[swz(n4 + j, ci0 * 2)]) = pk;
      }
    }
    __syncthreads();                      // drains glds (vmcnt) + lds writes
    // ---- MFMA ----
    #pragma unroll
    for (int ks = 0; ks < 2; ++ks) {
      const int kb = ks * 64 + (lane >> 4) * 16;
      bf16x8 fb[4], fa0[4];
      #pragma unroll
      for (int ni = 0; ni < 4; ++ni)
        fb[ni] = *reinterpret_cast<const bf16x8*>(&sB[swz(ni * 16 + (lane & 15), kb)]);
      #pragma unroll
      for (int mi = 0; mi < 4; ++mi)
        fa0[mi] = *reinterpret_cast<const bf16x8*>(&sA0[swz(w * 64 + mi * 16 + (lane & 15), kb)]);
      #pragma unroll
      for (int mi = 0; mi < 4; ++mi)
        #pragma unroll
        for (int ni = 0; ni < 4; ++ni)
          acc0[mi][ni] = __builtin_amdgcn_mfma_f32_16x16x32_bf16(fa0[mi], fb[ni], acc0[mi][ni], 0, 0, 0);
      if constexpr (NOUT == 2) {
        bf16x8 fa1[4];
        #pragma unroll
        for (int mi = 0; mi < 4; ++mi)
          fa1[mi] = *reinterpret_cast<const bf16x8*>(&sA1[swz(w * 64 + mi * 16 + (lane & 15), kb)]);
        #pragma unroll
        for (int mi = 0; mi < 4; ++mi)
          #pragma unroll
          for (int ni = 0; ni < 4; ++ni)
            acc1[mi][ni] = __builtin_amdgcn_mfma_f32_16x16x32_bf16(fa1[mi], fb[ni], acc1[mi][ni], 0, 0, 0);
      }
    }
  }
  // ---- epilogue 0: plain [b][co][n] bf16 (qry / key) ----
  #pragma unroll
  for (int mi = 0; mi < 4; ++mi) {
    const int coB = w * 64 + mi * 16 + ((lane >> 4) << 2);
    #pragma unroll
    for (int ni = 0; ni < 4; ++ni) {
      const int n = n0 + ni * 16 + (lane & 15);
      #pragma unroll
      for (int r = 0; r < 4; ++r) {
        const int co = coB + r;
        dst0[((size_t)b * CH + co) * NSP + n] = f2b(acc0[mi][ni][r] + bias0[co]);
      }
    }
  }
  // ---- epilogue 1: value -> val_t (transposed, row-swizzled) via LDS ----
  if constexpr (NOUT == 2) {
    __syncthreads();                      // sA0 now free
    #pragma unroll
    for (int mi = 0; mi < 4; ++mi) {
      const int co0 = w * 64 + mi * 16 + ((lane >> 4) << 2);
      #pragma unroll
      for (int ni = 0; ni < 4; ++ni) {
        const int nl = ni * 16 + (lane & 15);
        uint64_t pk = (uint64_t)f2b(acc1[mi][ni][0] + bias1[co0])
                    | ((uint64_t)f2b(acc1[mi][ni][1] + bias1[co0 + 1]) << 16)
                    | ((uint64_t)f2b(acc1[mi][ni][2] + bias1[co0 + 2]) << 32)
                    | ((uint64_t)f2b(acc1[mi][ni][3] + bias1[co0 + 3]) << 48);
        *reinterpret_cast<uint64_t*>(&sA0[nl * 512 + ((co0 * 2) ^ ((nl & 7) << 4))]) = pk;
      }
    }
    __syncthreads();
    // linear copy-out: image already swizzled exactly as stored in global
    char* vb = valt + (size_t)b * (NSP * 512) + (size_t)n0 * 512;
    #pragma unroll
    for (int i = 0; i < 8; ++i) {
      *reinterpret_cast<uint4*>(vb + tid * 128 + i * 16) =
          *reinterpret_cast<const uint4*>(sA0 + tid * 128 + i * 16);
    }
  }
}

// ---------------------------------------------------------------------------
// K2: split-K score partials (validated round 2).
// ---------------------------------------------------------------------------
__global__ __launch_bounds__(256)
void scores_kernel(const ushort_t* __restrict__ qry, const ushort_t* __restrict__ key,
                   float* __restrict__ part) {
  const int b  = blockIdx.z;
  const int s  = blockIdx.y;
  const int c0 = (blockIdx.x >> 1) * 128;
  const int d0 = (blockIdx.x & 1) * 128;
  const int tid  = threadIdx.x;
  const int lane = tid & 63;
  const int wm = (tid >> 7) & 1;
  const int wn = (tid >> 6) & 1;

  __shared__ __align__(16) unsigned char sQ[128 * 128];
  __shared__ __align__(16) unsigned char sK[128 * 128];

  f32x4 acc[4][4];
  #pragma unroll
  for (int i = 0; i < 4; ++i)
    #pragma unroll
    for (int j = 0; j < 4; ++j)
      #pragma unroll
      for (int r = 0; r < 4; ++r) acc[i][j][r] = 0.f;

  for (int kc = 0; kc < KSEG / 64; ++kc) {
    const int k0 = s * KSEG + kc * 64;
    #pragma unroll
    for (int it = 0; it < 4; ++it) {
      int slot = it * 256 + tid;
      int row  = slot >> 3;
      int seg  = slot & 7;
      *reinterpret_cast<uint4*>(&sQ[swz(row, seg * 16)]) =
          *reinterpret_cast<const uint4*>(qry + ((size_t)b * CH + c0 + row) * NSP + k0 + seg * 8);
      *reinterpret_cast<uint4*>(&sK[swz(row, seg * 16)]) =
          *reinterpret_cast<const uint4*>(key + ((size_t)b * CH + d0 + row) * NSP + k0 + seg * 8);
    }
    __syncthreads();
    #pragma unroll
    for (int ks = 0; ks < 2; ++ks) {
      const int kb = ks * 64 + (lane >> 4) * 16;
      bf16x8 fq[4], fk[4];
      #pragma unroll
      for (int mi = 0; mi < 4; ++mi)
        fq[mi] = *reinterpret_cast<const bf16x8*>(&sQ[swz(wm * 64 + mi * 16 + (lane & 15), kb)]);
      #pragma unroll
      for (int ni = 0; ni < 4; ++ni)
        fk[ni] = *reinterpret_cast<const bf16x8*>(&sK[swz(wn * 64 + ni * 16 + (lane & 15), kb)]);
      #pragma unroll
      for (int mi = 0; mi < 4; ++mi)
        #pragma unroll
        for (int ni = 0; ni < 4; ++ni)
          acc[mi][ni] = __builtin_amdgcn_mfma_f32_16x16x32_bf16(fq[mi], fk[ni], acc[mi][ni], 0, 0, 0);
    }
    __syncthreads();
  }
  const size_t base = ((size_t)b * NSPLIT + s) * CH;
  #pragma unroll
  for (int mi = 0; mi < 4; ++mi) {
    #pragma unroll
    for (int ni = 0; ni < 4; ++ni) {
      #pragma unroll
      for (int r = 0; r < 4; ++r) {
        int c = c0 + wm * 64 + mi * 16 + ((lane >> 4) << 2) + r;
        int d = d0 + wn * 64 + ni * 16 + (lane & 15);
        part[(base + c) * CH + d] = acc[mi][ni][r];
      }
    }
  }
}

// ---------------------------------------------------------------------------
// K3: reduce partials + softmax (validated round 2).
// ---------------------------------------------------------------------------
__global__ __launch_bounds__(64)
void softmax_kernel(const float* __restrict__ part, ushort_t* __restrict__ attn) {
  const int c = blockIdx.x;
  const int b = blockIdx.y;
  const int lane = threadIdx.x;
  float sv[4] = {0.f, 0.f, 0.f, 0.f};
  for (int sp = 0; sp < NSPLIT; ++sp) {
    const float* p = part + (((size_t)b * NSPLIT + sp) * CH + c) * CH;
    #pragma unroll
    for (int r = 0; r < 4; ++r) sv[r] += p[r * 64 + lane];
  }
  #pragma unroll
  for (int r = 0; r < 4; ++r) sv[r] *= (1.0f / 96.0f);   // /= sqrt(9216)
  float m = fmaxf(fmaxf(sv[0], sv[1]), fmaxf(sv[2], sv[3]));
  for (int off = 32; off > 0; off >>= 1) m = fmaxf(m, __shfl_xor(m, off));
  float e[4]; float sum = 0.f;
  #pragma unroll
  for (int r = 0; r < 4; ++r) { e[r] = expf(sv[r] - m); sum += e[r]; }
  for (int off = 32; off > 0; off >>= 1) sum += __shfl_xor(sum, off);
  float inv = 1.0f / sum;
  ushort_t* ap = attn + ((size_t)b * CH + c) * CH;
  #pragma unroll
  for (int r = 0; r < 4; ++r) ap[r * 64 + lane] = f2b(e[r] * inv);
}

// ---------------------------------------------------------------------------
// K4 MEGA: attn-out + BN + LeakyReLU + conv1 + LeakyReLU + conv2, fused.
// Tile by spatial residue s = n mod 36 and channel quarter c0:
//   n = s + 36j  =>  permute channel cp = j, spatial n' = s*256 + c.
// Phase 1: out[c, j] = sum_d attn[c0+c][d] * val_t[s+36j][d]   (c:64, j:256)
//          -> BN(ch=j) + lrelu -> t LDS image [c][j] (512B rows, key c&7)
// Phase 2: o1[co, c] = lrelu(sum_j W1[co][j] * t[j][n'] + b1) -> LDS [c][co]
// Phase 3: o2[co, c] = sum_co1 W2[co][co1] * o1 + b2 -> d_out fp32.
// LDS: sS[0,8K) sV[8K,40K) sT[40K,72K) sW[72K,104K) sO=[0,32K) (reuse).
// ---------------------------------------------------------------------------
__global__ __launch_bounds__(512)
void mega_kernel(const ushort_t* __restrict__ attn, const char* __restrict__ valt,
                 const ushort_t* __restrict__ w1sw, const float* __restrict__ bo1,
                 const ushort_t* __restrict__ w2sw, const float* __restrict__ bo2,
                 const float* __restrict__ gamma, const float* __restrict__ beta,
                 const float* __restrict__ mean,  const float* __restrict__ var,
                 float* __restrict__ out) {
  const int b    = blockIdx.y;
  const int s    = blockIdx.x >> 2;
  const int c0   = (blockIdx.x & 3) * 64;
  const int tid  = threadIdx.x;
  const int lane = tid & 63;
  const int w    = tid >> 6;            // 8 waves

  __shared__ __align__(16) unsigned char L[104 * 1024];
  unsigned char* sS = L;                 // [64 c][128B] per chunk
  unsigned char* sV = L + 8192;          // [256 j][128B] per chunk
  unsigned char* sT = L + 40960;         // [64 c][512B] (all 256 j)
  unsigned char* sW = L + 73728;         // [256 co][128B] per chunk
  unsigned char* sO = L;                 // [64 c][512B] (all 256 co1)

  const ushort_t* attn_b = attn + (size_t)b * 65536;
  const char*     vt_b   = valt + (size_t)b * (NSP * 512);

  // ---------------- phase 1 ----------------
  f32x4 acc[4][2];
  #pragma unroll
  for (int i = 0; i < 4; ++i)
    #pragma unroll
    for (int j = 0; j < 2; ++j)
      #pragma unroll
      for (int r = 0; r < 4; ++r) acc[i][j][r] = 0.f;

  for (int kc = 0; kc < 4; ++kc) {
    if (kc > 0) __syncthreads();
    {   // stage attn chunk: 64 rows x 128B, one uint4 per thread
      int row = tid >> 3, seg = tid & 7;
      *reinterpret_cast<uint4*>(&sS[swz(row, seg * 16)]) =
          *reinterpret_cast<const uint4*>(attn_b + (c0 + row) * 256 + kc * 64 + seg * 8);
    }
    #pragma unroll
    for (int it = 0; it < 4; ++it) {   // stage val_t rows s+36j, re-key n&7 -> j&7
      int slot = it * 512 + tid;
      int j = slot >> 3, seg = slot & 7;
      int n = s + 36 * j;
      uint4 dv = *reinterpret_cast<const uint4*>(
          vt_b + n * 512 + ((kc * 128 + seg * 16) ^ ((n & 7) << 4)));
      *reinterpret_cast<uint4*>(&sV[swz(j, seg * 16)]) = dv;
    }
    __syncthreads();
    #pragma unroll
    for (int ks = 0; ks < 2; ++ks) {
      const int kb = ks * 64 + (lane >> 4) * 16;
      bf16x8 fa[4], fb[2];
      #pragma unroll
      for (int mi = 0; mi < 4; ++mi)
        fa[mi] = *reinterpret_cast<const bf16x8*>(&sS[swz(mi * 16 + (lane & 15), kb)]);
      #pragma unroll
      for (int ni = 0; ni < 2; ++ni)
        fb[ni] = *reinterpret_cast<const bf16x8*>(&sV[swz(w * 32 + ni * 16 + (lane & 15), kb)]);
      #pragma unroll
      for (int mi = 0; mi < 4; ++mi)
        #pragma unroll
        for (int ni = 0; ni < 2; ++ni)
          acc[mi][ni] = __builtin_amdgcn_mfma_f32_16x16x32_bf16(fa[mi], fb[ni], acc[mi][ni], 0, 0, 0);
    }
  }
  // epilogue 1: BN(ch=j) + lrelu -> sT (disjoint region; no barrier needed yet)
  {
    float kf[2], bb[2];
    #pragma unroll
    for (int ni = 0; ni < 2; ++ni) {
      int j = w * 32 + ni * 16 + (lane & 15);
      float iv = rsqrtf(var[j] + 1e-4f);
      kf[ni] = gamma[j] * iv;
      bb[ni] = beta[j] - mean[j] * kf[ni];
    }
    #pragma unroll
    for (int mi = 0; mi < 4; ++mi)
      #pragma unroll
      for (int ni = 0; ni < 2; ++ni) {
        int j = w * 32 + ni * 16 + (lane & 15);
        #pragma unroll
        for (int r = 0; r < 4; ++r) {
          int cl = mi * 16 + ((lane >> 4) << 2) + r;
          float x = acc[mi][ni][r] * kf[ni] + bb[ni];
          x = (x >= 0.f) ? x : 0.01f * x;
          *reinterpret_cast<ushort_t*>(&sT[cl * 512 + ((j * 2) ^ ((cl & 7) << 4))]) = f2b(x);
        }
      }
  }
  __syncthreads();

  // ---------------- phase 2: conv1 (K = 256 j from sT, W1 via glds) --------
  f32x4 a2[2][4];
  #pragma unroll
  for (int i = 0; i < 2; ++i)
    #pragma unroll
    for (int j = 0; j < 4; ++j)
      #pragma unroll
      for (int r = 0; r < 4; ++r) a2[i][j][r] = 0.f;

  for (int kc = 0; kc < 4; ++kc) {
    if (kc > 0) __syncthreads();
    #pragma unroll
    for (int it = 0; it < 4; ++it) {
      int seg = (it * 8 + w) * 1024;
      glds16((const char*)w1sw + kc * 32768 + seg + lane * 16, (void*)(sW + seg));
    }
    __syncthreads();
    #pragma unroll
    for (int ks = 0; ks < 2; ++ks) {
      const int kbw = ks * 64 + (lane >> 4) * 16;          // within W chunk row
      const int kbt = kc * 128 + kbw;                      // within 512B t row
      bf16x8 fa2[2], fb2[4];
      #pragma unroll
      for (int mi = 0; mi < 2; ++mi)
        fa2[mi] = *reinterpret_cast<const bf16x8*>(&sW[swz(w * 32 + mi * 16 + (lane & 15), kbw)]);
      #pragma unroll
      for (int ni = 0; ni < 4; ++ni) {
        int cl = ni * 16 + (lane & 15);
        fb2[ni] = *reinterpret_cast<const bf16x8*>(&sT[cl * 512 + (kbt ^ ((cl & 7) << 4))]);
      }
      #pragma unroll
      for (int mi = 0; mi < 2; ++mi)
        #pragma unroll
        for (int ni = 0; ni < 4; ++ni)
          a2[mi][ni] = __builtin_amdgcn_mfma_f32_16x16x32_bf16(fa2[mi], fb2[ni], a2[mi][ni], 0, 0, 0);
    }
  }
  // epilogue 2: +bias, lrelu -> sO [c][co1] (b64 rows; sS/sV dead)
  #pragma unroll
  for (int mi = 0; mi < 2; ++mi) {
    const int co0 = w * 32 + mi * 16 + ((lane >> 4) << 2);
    #pragma unroll
    for (int ni = 0; ni < 4; ++ni) {
      const int cl = ni * 16 + (lane & 15);
      float y[4];
      #pragma unroll
      for (int r = 0; r < 4; ++r) {
        y[r] = a2[mi][ni][r] + bo1[co0 + r];
        y[r] = (y[r] >= 0.f) ? y[r] : 0.01f * y[r];
      }
      uint64_t pk = (uint64_t)f2b(y[0]) | ((uint64_t)f2b(y[1]) << 16)
                  | ((uint64_t)f2b(y[2]) << 32) | ((uint64_t)f2b(y[3]) << 48);
      *reinterpret_cast<uint64_t*>(&sO[cl * 512 + ((co0 * 2) ^ ((cl & 7) << 4))]) = pk;
    }
  }
  __syncthreads();

  // ---------------- phase 3: conv2 (K = 256 co1 from sO, W2 via glds) ------
  f32x4 a3[2][4];
  #pragma unroll
  for (int i = 0; i < 2; ++i)
    #pragma unroll
    for (int j = 0; j < 4; ++j)
      #pragma unroll
      for (int r = 0; r < 4; ++r) a3[i][j][r] = 0.f;

  for (int kc = 0; kc < 4; ++kc) {
    if (kc > 0) __syncthreads();
    #pragma unroll
    for (int it = 0; it < 4; ++it) {
      int seg = (it * 8 + w) * 1024;
      glds16((const char*)w2sw + kc * 32768 + seg + lane * 16, (void*)(sW + seg));
    }
    __syncthreads();
    #pragma unroll
    for (int ks = 0; ks < 2; ++ks) {
      const int kbw = ks * 64 + (lane >> 4) * 16;
      const int kbt = kc * 128 + kbw;
      bf16x8 fa3[2], fb3[4];
      #pragma unroll
      for (int mi = 0; mi < 2; ++mi)
        fa3[mi] = *reinterpret_cast<const bf16x8*>(&sW[swz(w * 32 + mi * 16 + (lane & 15), kbw)]);
      #pragma unroll
      for (int ni = 0; ni < 4; ++ni) {
        int cl = ni * 16 + (lane & 15);
        fb3[ni] = *reinterpret_cast<const bf16x8*>(&sO[cl * 512 + (kbt ^ ((cl & 7) << 4))]);
      }
      #pragma unroll
      for (int mi = 0; mi < 2; ++mi)
        #pragma unroll
        for (int ni = 0; ni < 4; ++ni)
          a3[mi][ni] = __builtin_amdgcn_mfma_f32_16x16x32_bf16(fa3[mi], fb3[ni], a3[mi][ni], 0, 0, 0);
    }
  }
  // final store fp32: out[b][co][s*256 + c0 + cl]
  #pragma unroll
  for (int mi = 0; mi < 2; ++mi) {
    const int coB = w * 32 + mi * 16 + ((lane >> 4) << 2);
    #pragma unroll
    for (int ni = 0; ni < 4; ++ni) {
      const int cl = ni * 16 + (lane & 15);
      #pragma unroll
      for (int r = 0; r < 4; ++r) {
        const int co = coB + r;
        out[(size_t)b * (CH * NSP) + (size_t)co * NSP + s * 256 + c0 + cl] =
            a3[mi][ni][r] + bo2[co];
      }
    }
  }
}

// ---------------------------------------------------------------------------
// Launch. Workspace (~56.2 MB):
//   [0)        5 x 128KB swizzled bf16 weight images (Wq,Wk,Wv,Wo1,Wo2)
//   [655360)   val_t swizzled bf16 [b][n][d] (37748736 B)
//   [38404096) score partials fp32 (16777216 B)
//   [55181312) attn bf16 (1048576 B)
// d_out doubles as scratch: qry/key bf16 (dead after scores; MEGA overwrites).
// ---------------------------------------------------------------------------
extern "C" void kernel_launch(void* const* d_in, const int* in_sizes, int n_in,
                              void* d_out, int out_size, void* d_ws, size_t ws_size,
                              hipStream_t stream) {
  (void)in_sizes; (void)n_in; (void)out_size; (void)ws_size;
  const float* q   = (const float*)d_in[0];
  const float* v   = (const float*)d_in[1];
  const float* Wq  = (const float*)d_in[2];
  const float* bq  = (const float*)d_in[3];
  const float* Wk  = (const float*)d_in[4];
  const float* bk  = (const float*)d_in[5];
  const float* Wv  = (const float*)d_in[6];
  const float* bv  = (const float*)d_in[7];
  const float* bng = (const float*)d_in[8];
  const float* bnb = (const float*)d_in[9];
  const float* bnm = (const float*)d_in[10];
  const float* bnv = (const float*)d_in[11];
  const float* Wo1 = (const float*)d_in[12];
  const float* bo1 = (const float*)d_in[13];
  const float* Wo2 = (const float*)d_in[14];
  const float* bo2 = (const float*)d_in[15];

  char* ws = (char*)d_ws;
  ushort_t* wq_b  = (ushort_t*)(ws);
  ushort_t* wk_b  = (ushort_t*)(ws + 131072);
  ushort_t* wv_b  = (ushort_t*)(ws + 262144);
  ushort_t* wo1_b = (ushort_t*)(ws + 393216);
  ushort_t* wo2_b = (ushort_t*)(ws + 524288);
  char*     valt  = ws + 655360;
  float*    part  = (float*)   (ws + 655360 + 37748736);
  ushort_t* attn  = (ushort_t*)(ws + 655360 + 37748736 + 16777216);
  ushort_t* qry   = (ushort_t*)d_out;  // scratch (dead before MEGA writes)
  ushort_t* key   = qry + 18874368;

  wconv_kernel<<<160, 256, 0, stream>>>(Wq, Wk, Wv, Wo1, Wo2, wq_b);

  dim3 g1(NSP / 64, NBATCH);
  // q -> query (plain) and value (transposed val_t) in one pass over q
  proj_kernel<2><<<g1, 256, 0, stream>>>(wq_b, bq, qry, wv_b, bv, valt, q);
  // v -> key (plain)
  proj_kernel<1><<<g1, 256, 0, stream>>>(wk_b, bk, key, nullptr, nullptr, nullptr, v);

  scores_kernel<<<dim3(4, NSPLIT, NBATCH), 256, 0, stream>>>(qry, key, part);
  softmax_kernel<<<dim3(CH, NBATCH), 64, 0, stream>>>(part, attn);

  mega_kernel<<<dim3(144, NBATCH), 512, 0, stream>>>(
      attn, valt, wo1_b, bo1, wo2_b, bo2, bng, bnb, bnm, bnv, (float*)d_out);
}

// Round 6
// 380.248 us; speedup vs baseline: 1.1588x; 1.0602x over previous
//
#include <hip/hip_runtime.h>
#include <hip/hip_bf16.h>
#include <stdint.h>

// Problem constants
#define CH     256
#define NSP    9216
#define NBATCH 8
#define NSPLIT 8
#define KSEG   1152  // NSP / NSPLIT

typedef unsigned short ushort_t;
using f32x4  = __attribute__((ext_vector_type(4))) float;
using bf16x8 = __attribute__((ext_vector_type(8))) short;

__device__ __forceinline__ ushort_t f2b(float f) {
  union { float f; uint32_t u; } v; v.f = f;
  return (ushort_t)((v.u + 0x7FFFu + ((v.u >> 16) & 1u)) >> 16);
}

// XOR swizzle for 128-byte LDS rows (key = row&7, moves 16B slots).
__device__ __forceinline__ uint32_t swz(uint32_t row, uint32_t byte) {
  return row * 128u + (byte ^ ((row & 7u) << 4));
}

// global -> LDS async DMA, 16B per lane. lds base must be wave-uniform;
// global address is per-lane.
typedef __attribute__((address_space(3))) void       lds_void;
typedef const __attribute__((address_space(1))) void g_void;
__device__ __forceinline__ void glds16(const void* g, void* l) {
  __builtin_amdgcn_global_load_lds((g_void*)g, (lds_void*)l, 16, 0, 0);
}

// ---------------------------------------------------------------------------
// K0: weights fp32 -> bf16.
//  m in {0,1,2} (Wq,Wk,Wv): chunk-swizzled images [kc][co][128B swz row]
//    (consumed via global_load_lds by proj_kernel)
//  m in {3,4}   (Wo1,Wo2): plain row-major bf16 (consumed directly from L2
//    by mega_kernel's phases 2/3 — k-contiguous fragments)
// ---------------------------------------------------------------------------
__global__ void wconv_kernel(const float* __restrict__ w0, const float* __restrict__ w1,
                             const float* __restrict__ w2, const float* __restrict__ w3,
                             const float* __restrict__ w4, ushort_t* __restrict__ dst) {
  int gid = blockIdx.x * 256 + threadIdx.x;   // 40960 16B-units total
  int m   = gid >> 13;                        // matrix id (8192 units each)
  int u   = gid & 8191;
  const float* W = (m == 0) ? w0 : (m == 1) ? w1 : (m == 2) ? w2 : (m == 3) ? w3 : w4;
  int lin = u * 16;                           // byte offset within 128KB image
  const float* srow;
  if (m < 3) {
    int kc  = lin >> 15;
    int co  = (lin >> 7) & 255;
    int bb0 = lin & 127;                      // 16B-aligned
    int k0  = kc * 64 + ((bb0 ^ ((co & 7) << 4)) >> 1); // 8-elem aligned
    srow = W + co * 256 + k0;
  } else {
    srow = W + u * 8;                         // plain row-major
  }
  float4 a = *reinterpret_cast<const float4*>(srow);
  float4 c = *reinterpret_cast<const float4*>(srow + 4);
  ushort_t o[8] = {f2b(a.x), f2b(a.y), f2b(a.z), f2b(a.w),
                   f2b(c.x), f2b(c.y), f2b(c.z), f2b(c.w)};
  uint4 pk;
  pk.x = (uint32_t)o[0] | ((uint32_t)o[1] << 16);
  pk.y = (uint32_t)o[2] | ((uint32_t)o[3] << 16);
  pk.z = (uint32_t)o[4] | ((uint32_t)o[5] << 16);
  pk.w = (uint32_t)o[6] | ((uint32_t)o[7] << 16);
  *reinterpret_cast<uint4*>(dst + m * 65536 + (lin >> 1)) = pk;
}

// ---------------------------------------------------------------------------
// K1: projection GEMM dst[b,co,n] = sum_ci A[co,ci]*src[b,ci,n] + bias.
// A from pre-swizzled image via global_load_lds. src fp32. Tile 256co x 64n.
// NOUT=2: second output (value) is written TRANSPOSED+swizzled: val_t[n][d]
// rows of 512B with 16B slots XORed by (n&7)<<4 (so MEGA can re-key cheaply).
// (unchanged from round 5 — validated)
// ---------------------------------------------------------------------------
template<int NOUT>
__global__ __launch_bounds__(256)
void proj_kernel(const ushort_t* __restrict__ Asw0, const float* __restrict__ bias0,
                 ushort_t* __restrict__ dst0,
                 const ushort_t* __restrict__ Asw1, const float* __restrict__ bias1,
                 char* __restrict__ valt,
                 const float* __restrict__ src) {
  const int b    = blockIdx.y;
  const int n0   = blockIdx.x * 64;
  const int tid  = threadIdx.x;
  const int lane = tid & 63;
  const int w    = tid >> 6;

  __shared__ __align__(16) unsigned char sA0[32768];
  __shared__ __align__(16) unsigned char sA1[(NOUT == 2) ? 32768 : 16];
  __shared__ __align__(16) unsigned char sB[8192];

  f32x4 acc0[4][4];
  f32x4 acc1[4][4];
  #pragma unroll
  for (int i = 0; i < 4; ++i)
    #pragma unroll
    for (int j = 0; j < 4; ++j)
      #pragma unroll
      for (int r = 0; r < 4; ++r) { acc0[i][j][r] = 0.f; acc1[i][j][r] = 0.f; }

  for (int kc = 0; kc < 4; ++kc) {
    const int k0 = kc * 64;
    if (kc > 0) __syncthreads();          // protect LDS from previous readers
    // ---- A chunks via global_load_lds (linear copy of pre-swizzled image) --
    #pragma unroll
    for (int it = 0; it < 8; ++it) {
      int seg = (it * 4 + w) * 1024;      // wave-uniform 1KB segment
      glds16((const char*)Asw0 + kc * 32768 + seg + lane * 16,
             (void*)(sA0 + seg));
      if constexpr (NOUT == 2)
        glds16((const char*)Asw1 + kc * 32768 + seg + lane * 16,
               (void*)(sA1 + seg));
    }
    // ---- B chunk: fp32 [ci][n] -> bf16 LDS [n][ci] swizzled, packed b64 ----
    {
      const int ci0 = (tid >> 4) * 4;     // 4 consecutive ci
      const int n4  = (tid & 15) * 4;     // 4 consecutive n
      float xv[4][4];
      #pragma unroll
      for (int r = 0; r < 4; ++r) {
        float4 t4 = *reinterpret_cast<const float4*>(
            src + ((size_t)b * CH + (k0 + ci0 + r)) * NSP + n0 + n4);
        xv[r][0] = t4.x; xv[r][1] = t4.y; xv[r][2] = t4.z; xv[r][3] = t4.w;
      }
      #pragma unroll
      for (int j = 0; j < 4; ++j) {
        uint64_t pk = (uint64_t)f2b(xv[0][j])
                    | ((uint64_t)f2b(xv[1][j]) << 16)
                    | ((uint64_t)f2b(xv[2][j]) << 32)
                    | ((uint64_t)f2b(xv[3][j]) << 48);
        *reinterpret_cast<uint64_t*>(&sB[swz(n4 + j, ci0 * 2)]) = pk;
      }
    }
    __syncthreads();                      // drains glds (vmcnt) + lds writes
    // ---- MFMA ----
    #pragma unroll
    for (int ks = 0; ks < 2; ++ks) {
      const int kb = ks * 64 + (lane >> 4) * 16;
      bf16x8 fb[4], fa0[4];
      #pragma unroll
      for (int ni = 0; ni < 4; ++ni)
        fb[ni] = *reinterpret_cast<const bf16x8*>(&sB[swz(ni * 16 + (lane & 15), kb)]);
      #pragma unroll
      for (int mi = 0; mi < 4; ++mi)
        fa0[mi] = *reinterpret_cast<const bf16x8*>(&sA0[swz(w * 64 + mi * 16 + (lane & 15), kb)]);
      #pragma unroll
      for (int mi = 0; mi < 4; ++mi)
        #pragma unroll
        for (int ni = 0; ni < 4; ++ni)
          acc0[mi][ni] = __builtin_amdgcn_mfma_f32_16x16x32_bf16(fa0[mi], fb[ni], acc0[mi][ni], 0, 0, 0);
      if constexpr (NOUT == 2) {
        bf16x8 fa1[4];
        #pragma unroll
        for (int mi = 0; mi < 4; ++mi)
          fa1[mi] = *reinterpret_cast<const bf16x8*>(&sA1[swz(w * 64 + mi * 16 + (lane & 15), kb)]);
        #pragma unroll
        for (int mi = 0; mi < 4; ++mi)
          #pragma unroll
          for (int ni = 0; ni < 4; ++ni)
            acc1[mi][ni] = __builtin_amdgcn_mfma_f32_16x16x32_bf16(fa1[mi], fb[ni], acc1[mi][ni], 0, 0, 0);
      }
    }
  }
  // ---- epilogue 0: plain [b][co][n] bf16 (qry / key) ----
  #pragma unroll
  for (int mi = 0; mi < 4; ++mi) {
    const int coB = w * 64 + mi * 16 + ((lane >> 4) << 2);
    #pragma unroll
    for (int ni = 0; ni < 4; ++ni) {
      const int n = n0 + ni * 16 + (lane & 15);
      #pragma unroll
      for (int r = 0; r < 4; ++r) {
        const int co = coB + r;
        dst0[((size_t)b * CH + co) * NSP + n] = f2b(acc0[mi][ni][r] + bias0[co]);
      }
    }
  }
  // ---- epilogue 1: value -> val_t (transposed, row-swizzled) via LDS ----
  if constexpr (NOUT == 2) {
    __syncthreads();                      // sA0 now free
    #pragma unroll
    for (int mi = 0; mi < 4; ++mi) {
      const int co0 = w * 64 + mi * 16 + ((lane >> 4) << 2);
      #pragma unroll
      for (int ni = 0; ni < 4; ++ni) {
        const int nl = ni * 16 + (lane & 15);
        uint64_t pk = (uint64_t)f2b(acc1[mi][ni][0] + bias1[co0])
                    | ((uint64_t)f2b(acc1[mi][ni][1] + bias1[co0 + 1]) << 16)
                    | ((uint64_t)f2b(acc1[mi][ni][2] + bias1[co0 + 2]) << 32)
                    | ((uint64_t)f2b(acc1[mi][ni][3] + bias1[co0 + 3]) << 48);
        *reinterpret_cast<uint64_t*>(&sA0[nl * 512 + ((co0 * 2) ^ ((nl & 7) << 4))]) = pk;
      }
    }
    __syncthreads();
    // linear copy-out: image already swizzled exactly as stored in global
    char* vb = valt + (size_t)b * (NSP * 512) + (size_t)n0 * 512;
    #pragma unroll
    for (int i = 0; i < 8; ++i) {
      *reinterpret_cast<uint4*>(vb + tid * 128 + i * 16) =
          *reinterpret_cast<const uint4*>(sA0 + tid * 128 + i * 16);
    }
  }
}

// ---------------------------------------------------------------------------
// K2: split-K score partials (validated round 2).
// ---------------------------------------------------------------------------
__global__ __launch_bounds__(256)
void scores_kernel(const ushort_t* __restrict__ qry, const ushort_t* __restrict__ key,
                   float* __restrict__ part) {
  const int b  = blockIdx.z;
  const int s  = blockIdx.y;
  const int c0 = (blockIdx.x >> 1) * 128;
  const int d0 = (blockIdx.x & 1) * 128;
  const int tid  = threadIdx.x;
  const int lane = tid & 63;
  const int wm = (tid >> 7) & 1;
  const int wn = (tid >> 6) & 1;

  __shared__ __align__(16) unsigned char sQ[128 * 128];
  __shared__ __align__(16) unsigned char sK[128 * 128];

  f32x4 acc[4][4];
  #pragma unroll
  for (int i = 0; i < 4; ++i)
    #pragma unroll
    for (int j = 0; j < 4; ++j)
      #pragma unroll
      for (int r = 0; r < 4; ++r) acc[i][j][r] = 0.f;

  for (int kc = 0; kc < KSEG / 64; ++kc) {
    const int k0 = s * KSEG + kc * 64;
    #pragma unroll
    for (int it = 0; it < 4; ++it) {
      int slot = it * 256 + tid;
      int row  = slot >> 3;
      int seg  = slot & 7;
      *reinterpret_cast<uint4*>(&sQ[swz(row, seg * 16)]) =
          *reinterpret_cast<const uint4*>(qry + ((size_t)b * CH + c0 + row) * NSP + k0 + seg * 8);
      *reinterpret_cast<uint4*>(&sK[swz(row, seg * 16)]) =
          *reinterpret_cast<const uint4*>(key + ((size_t)b * CH + d0 + row) * NSP + k0 + seg * 8);
    }
    __syncthreads();
    #pragma unroll
    for (int ks = 0; ks < 2; ++ks) {
      const int kb = ks * 64 + (lane >> 4) * 16;
      bf16x8 fq[4], fk[4];
      #pragma unroll
      for (int mi = 0; mi < 4; ++mi)
        fq[mi] = *reinterpret_cast<const bf16x8*>(&sQ[swz(wm * 64 + mi * 16 + (lane & 15), kb)]);
      #pragma unroll
      for (int ni = 0; ni < 4; ++ni)
        fk[ni] = *reinterpret_cast<const bf16x8*>(&sK[swz(wn * 64 + ni * 16 + (lane & 15), kb)]);
      #pragma unroll
      for (int mi = 0; mi < 4; ++mi)
        #pragma unroll
        for (int ni = 0; ni < 4; ++ni)
          acc[mi][ni] = __builtin_amdgcn_mfma_f32_16x16x32_bf16(fq[mi], fk[ni], acc[mi][ni], 0, 0, 0);
    }
    __syncthreads();
  }
  const size_t base = ((size_t)b * NSPLIT + s) * CH;
  #pragma unroll
  for (int mi = 0; mi < 4; ++mi) {
    #pragma unroll
    for (int ni = 0; ni < 4; ++ni) {
      #pragma unroll
      for (int r = 0; r < 4; ++r) {
        int c = c0 + wm * 64 + mi * 16 + ((lane >> 4) << 2) + r;
        int d = d0 + wn * 64 + ni * 16 + (lane & 15);
        part[(base + c) * CH + d] = acc[mi][ni][r];
      }
    }
  }
}

// ---------------------------------------------------------------------------
// K3: reduce partials + softmax (validated round 2).
// ---------------------------------------------------------------------------
__global__ __launch_bounds__(64)
void softmax_kernel(const float* __restrict__ part, ushort_t* __restrict__ attn) {
  const int c = blockIdx.x;
  const int b = blockIdx.y;
  const int lane = threadIdx.x;
  float sv[4] = {0.f, 0.f, 0.f, 0.f};
  for (int sp = 0; sp < NSPLIT; ++sp) {
    const float* p = part + (((size_t)b * NSPLIT + sp) * CH + c) * CH;
    #pragma unroll
    for (int r = 0; r < 4; ++r) sv[r] += p[r * 64 + lane];
  }
  #pragma unroll
  for (int r = 0; r < 4; ++r) sv[r] *= (1.0f / 96.0f);   // /= sqrt(9216)
  float m = fmaxf(fmaxf(sv[0], sv[1]), fmaxf(sv[2], sv[3]));
  for (int off = 32; off > 0; off >>= 1) m = fmaxf(m, __shfl_xor(m, off));
  float e[4]; float sum = 0.f;
  #pragma unroll
  for (int r = 0; r < 4; ++r) { e[r] = expf(sv[r] - m); sum += e[r]; }
  for (int off = 32; off > 0; off >>= 1) sum += __shfl_xor(sum, off);
  float inv = 1.0f / sum;
  ushort_t* ap = attn + ((size_t)b * CH + c) * CH;
  #pragma unroll
  for (int r = 0; r < 4; ++r) ap[r * 64 + lane] = f2b(e[r] * inv);
}

// ---------------------------------------------------------------------------
// K4 MEGA: attn-out + BN + LeakyReLU + conv1 + LeakyReLU + conv2, fused.
// Round-6 changes (counter-driven):
//  * W1/W2 read directly from plain bf16 global (L2-hot) — sW staging and its
//    8 barriers removed.
//  * LDS 104KB -> 72KB  => 2 blocks/CU (Occupancy 20% -> ~40%).
//  * Bijective XCD swizzle: the 4 c0-siblings of each s land on one XCD's L2
//    (kills the 2x valt over-fetch; FETCH 80MB -> ~45MB predicted).
// LDS: sS[0,8K) sV[8K,40K) sT[40K,72K) sO=[0,32K) (reuse of dead sS/sV).
// ---------------------------------------------------------------------------
__global__ __launch_bounds__(512)
void mega_kernel(const ushort_t* __restrict__ attn, const char* __restrict__ valt,
                 const ushort_t* __restrict__ w1p, const float* __restrict__ bo1,
                 const ushort_t* __restrict__ w2p, const float* __restrict__ bo2,
                 const float* __restrict__ gamma, const float* __restrict__ beta,
                 const float* __restrict__ mean,  const float* __restrict__ var,
                 float* __restrict__ out) {
  // XCD swizzle over 1152 blocks (nwg%8==0 -> bijective): XCD x gets work
  // [x*144, (x+1)*144) = one full batch (valt slice 4.7MB ~ fits 4MB L2).
  const int lin = blockIdx.y * 144 + blockIdx.x;
  const int wid = (lin & 7) * 144 + (lin >> 3);
  const int b   = wid / 144;
  const int rr  = wid % 144;
  const int s   = rr >> 2;
  const int c0  = (rr & 3) * 64;
  const int tid  = threadIdx.x;
  const int lane = tid & 63;
  const int w    = tid >> 6;            // 8 waves

  __shared__ __align__(16) unsigned char L[72 * 1024];
  unsigned char* sS = L;                 // [64 c][128B] per chunk
  unsigned char* sV = L + 8192;          // [256 j][128B] per chunk
  unsigned char* sT = L + 40960;         // [64 c][512B] (all 256 j)
  unsigned char* sO = L;                 // [64 c][512B] (all 256 co1), reuse

  const ushort_t* attn_b = attn + (size_t)b * 65536;
  const char*     vt_b   = valt + (size_t)b * (NSP * 512);

  // ---------------- phase 1: attn @ val_t ----------------
  f32x4 acc[4][2];
  #pragma unroll
  for (int i = 0; i < 4; ++i)
    #pragma unroll
    for (int j = 0; j < 2; ++j)
      #pragma unroll
      for (int r = 0; r < 4; ++r) acc[i][j][r] = 0.f;

  for (int kc = 0; kc < 4; ++kc) {
    if (kc > 0) __syncthreads();
    {   // stage attn chunk: 64 rows x 128B, one uint4 per thread
      int row = tid >> 3, seg = tid & 7;
      *reinterpret_cast<uint4*>(&sS[swz(row, seg * 16)]) =
          *reinterpret_cast<const uint4*>(attn_b + (c0 + row) * 256 + kc * 64 + seg * 8);
    }
    #pragma unroll
    for (int it = 0; it < 4; ++it) {   // stage val_t rows s+36j, re-key n&7 -> j&7
      int slot = it * 512 + tid;
      int j = slot >> 3, seg = slot & 7;
      int n = s + 36 * j;
      uint4 dv = *reinterpret_cast<const uint4*>(
          vt_b + n * 512 + ((kc * 128 + seg * 16) ^ ((n & 7) << 4)));
      *reinterpret_cast<uint4*>(&sV[swz(j, seg * 16)]) = dv;
    }
    __syncthreads();
    #pragma unroll
    for (int ks = 0; ks < 2; ++ks) {
      const int kb = ks * 64 + (lane >> 4) * 16;
      bf16x8 fa[4], fb[2];
      #pragma unroll
      for (int mi = 0; mi < 4; ++mi)
        fa[mi] = *reinterpret_cast<const bf16x8*>(&sS[swz(mi * 16 + (lane & 15), kb)]);
      #pragma unroll
      for (int ni = 0; ni < 2; ++ni)
        fb[ni] = *reinterpret_cast<const bf16x8*>(&sV[swz(w * 32 + ni * 16 + (lane & 15), kb)]);
      #pragma unroll
      for (int mi = 0; mi < 4; ++mi)
        #pragma unroll
        for (int ni = 0; ni < 2; ++ni)
          acc[mi][ni] = __builtin_amdgcn_mfma_f32_16x16x32_bf16(fa[mi], fb[ni], acc[mi][ni], 0, 0, 0);
    }
  }
  // epilogue 1: BN(ch=j) + lrelu -> sT (disjoint region; no barrier needed yet)
  {
    float kf[2], bb[2];
    #pragma unroll
    for (int ni = 0; ni < 2; ++ni) {
      int j = w * 32 + ni * 16 + (lane & 15);
      float iv = rsqrtf(var[j] + 1e-4f);
      kf[ni] = gamma[j] * iv;
      bb[ni] = beta[j] - mean[j] * kf[ni];
    }
    #pragma unroll
    for (int mi = 0; mi < 4; ++mi)
      #pragma unroll
      for (int ni = 0; ni < 2; ++ni) {
        int j = w * 32 + ni * 16 + (lane & 15);
        #pragma unroll
        for (int r = 0; r < 4; ++r) {
          int cl = mi * 16 + ((lane >> 4) << 2) + r;
          float x = acc[mi][ni][r] * kf[ni] + bb[ni];
          x = (x >= 0.f) ? x : 0.01f * x;
          *reinterpret_cast<ushort_t*>(&sT[cl * 512 + ((j * 2) ^ ((cl & 7) << 4))]) = f2b(x);
        }
      }
  }
  __syncthreads();   // sT ready; all phase-1 LDS reads drained

  // ------- phase 2: conv1. K = 256 j from sT; W1 fragments from global -----
  f32x4 a2[2][4];
  #pragma unroll
  for (int i = 0; i < 2; ++i)
    #pragma unroll
    for (int j = 0; j < 4; ++j)
      #pragma unroll
      for (int r = 0; r < 4; ++r) a2[i][j][r] = 0.f;

  #pragma unroll
  for (int kc = 0; kc < 4; ++kc) {
    #pragma unroll
    for (int ks = 0; ks < 2; ++ks) {
      const int ke  = kc * 64 + ks * 32 + (lane >> 4) * 8;   // element offset
      const int kbt = kc * 128 + ks * 64 + (lane >> 4) * 16; // byte offset in sT row
      bf16x8 fa2[2], fb2[4];
      #pragma unroll
      for (int mi = 0; mi < 2; ++mi)
        fa2[mi] = *reinterpret_cast<const bf16x8*>(
            w1p + (w * 32 + mi * 16 + (lane & 15)) * 256 + ke);
      #pragma unroll
      for (int ni = 0; ni < 4; ++ni) {
        int cl = ni * 16 + (lane & 15);
        fb2[ni] = *reinterpret_cast<const bf16x8*>(&sT[cl * 512 + (kbt ^ ((cl & 7) << 4))]);
      }
      #pragma unroll
      for (int mi = 0; mi < 2; ++mi)
        #pragma unroll
        for (int ni = 0; ni < 4; ++ni)
          a2[mi][ni] = __builtin_amdgcn_mfma_f32_16x16x32_bf16(fa2[mi], fb2[ni], a2[mi][ni], 0, 0, 0);
    }
  }
  // epilogue 2: +bias, lrelu -> sO [c][co1] (sS/sV region is dead)
  #pragma unroll
  for (int mi = 0; mi < 2; ++mi) {
    const int co0 = w * 32 + mi * 16 + ((lane >> 4) << 2);
    #pragma unroll
    for (int ni = 0; ni < 4; ++ni) {
      const int cl = ni * 16 + (lane & 15);
      float y[4];
      #pragma unroll
      for (int r = 0; r < 4; ++r) {
        y[r] = a2[mi][ni][r] + bo1[co0 + r];
        y[r] = (y[r] >= 0.f) ? y[r] : 0.01f * y[r];
      }
      uint64_t pk = (uint64_t)f2b(y[0]) | ((uint64_t)f2b(y[1]) << 16)
                  | ((uint64_t)f2b(y[2]) << 32) | ((uint64_t)f2b(y[3]) << 48);
      *reinterpret_cast<uint64_t*>(&sO[cl * 512 + ((co0 * 2) ^ ((cl & 7) << 4))]) = pk;
    }
  }
  __syncthreads();   // sO ready

  // ------- phase 3: conv2. K = 256 co1 from sO; W2 fragments from global ---
  f32x4 a3[2][4];
  #pragma unroll
  for (int i = 0; i < 2; ++i)
    #pragma unroll
    for (int j = 0; j < 4; ++j)
      #pragma unroll
      for (int r = 0; r < 4; ++r) a3[i][j][r] = 0.f;

  #pragma unroll
  for (int kc = 0; kc < 4; ++kc) {
    #pragma unroll
    for (int ks = 0; ks < 2; ++ks) {
      const int ke  = kc * 64 + ks * 32 + (lane >> 4) * 8;
      const int kbt = kc * 128 + ks * 64 + (lane >> 4) * 16;
      bf16x8 fa3[2], fb3[4];
      #pragma unroll
      for (int mi = 0; mi < 2; ++mi)
        fa3[mi] = *reinterpret_cast<const bf16x8*>(
            w2p + (w * 32 + mi * 16 + (lane & 15)) * 256 + ke);
      #pragma unroll
      for (int ni = 0; ni < 4; ++ni) {
        int cl = ni * 16 + (lane & 15);
        fb3[ni] = *reinterpret_cast<const bf16x8*>(&sO[cl * 512 + (kbt ^ ((cl & 7) << 4))]);
      }
      #pragma unroll
      for (int mi = 0; mi < 2; ++mi)
        #pragma unroll
        for (int ni = 0; ni < 4; ++ni)
          a3[mi][ni] = __builtin_amdgcn_mfma_f32_16x16x32_bf16(fa3[mi], fb3[ni], a3[mi][ni], 0, 0, 0);
    }
  }
  // final store fp32: out[b][co][s*256 + c0 + cl]
  #pragma unroll
  for (int mi = 0; mi < 2; ++mi) {
    const int coB = w * 32 + mi * 16 + ((lane >> 4) << 2);
    #pragma unroll
    for (int ni = 0; ni < 4; ++ni) {
      const int cl = ni * 16 + (lane & 15);
      #pragma unroll
      for (int r = 0; r < 4; ++r) {
        const int co = coB + r;
        out[(size_t)b * (CH * NSP) + (size_t)co * NSP + s * 256 + c0 + cl] =
            a3[mi][ni][r] + bo2[co];
      }
    }
  }
}

// ---------------------------------------------------------------------------
// Launch. Workspace (~56.2 MB):
//   [0)        5 x 128KB bf16 weights (Wq,Wk,Wv swizzled; Wo1,Wo2 plain)
//   [655360)   val_t swizzled bf16 [b][n][d] (37748736 B)
//   [38404096) score partials fp32 (16777216 B)
//   [55181312) attn bf16 (1048576 B)
// d_out doubles as scratch: qry/key bf16 (dead after scores; MEGA overwrites).
// ---------------------------------------------------------------------------
extern "C" void kernel_launch(void* const* d_in, const int* in_sizes, int n_in,
                              void* d_out, int out_size, void* d_ws, size_t ws_size,
                              hipStream_t stream) {
  (void)in_sizes; (void)n_in; (void)out_size; (void)ws_size;
  const float* q   = (const float*)d_in[0];
  const float* v   = (const float*)d_in[1];
  const float* Wq  = (const float*)d_in[2];
  const float* bq  = (const float*)d_in[3];
  const float* Wk  = (const float*)d_in[4];
  const float* bk  = (const float*)d_in[5];
  const float* Wv  = (const float*)d_in[6];
  const float* bv  = (const float*)d_in[7];
  const float* bng = (const float*)d_in[8];
  const float* bnb = (const float*)d_in[9];
  const float* bnm = (const float*)d_in[10];
  const float* bnv = (const float*)d_in[11];
  const float* Wo1 = (const float*)d_in[12];
  const float* bo1 = (const float*)d_in[13];
  const float* Wo2 = (const float*)d_in[14];
  const float* bo2 = (const float*)d_in[15];

  char* ws = (char*)d_ws;
  ushort_t* wq_b  = (ushort_t*)(ws);
  ushort_t* wk_b  = (ushort_t*)(ws + 131072);
  ushort_t* wv_b  = (ushort_t*)(ws + 262144);
  ushort_t* wo1_b = (ushort_t*)(ws + 393216);   // plain bf16
  ushort_t* wo2_b = (ushort_t*)(ws + 524288);   // plain bf16
  char*     valt  = ws + 655360;
  float*    part  = (float*)   (ws + 655360 + 37748736);
  ushort_t* attn  = (ushort_t*)(ws + 655360 + 37748736 + 16777216);
  ushort_t* qry   = (ushort_t*)d_out;  // scratch (dead before MEGA writes)
  ushort_t* key   = qry + 18874368;

  wconv_kernel<<<160, 256, 0, stream>>>(Wq, Wk, Wv, Wo1, Wo2, wq_b);

  dim3 g1(NSP / 64, NBATCH);
  // q -> query (plain) and value (transposed val_t) in one pass over q
  proj_kernel<2><<<g1, 256, 0, stream>>>(wq_b, bq, qry, wv_b, bv, valt, q);
  // v -> key (plain)
  proj_kernel<1><<<g1, 256, 0, stream>>>(wk_b, bk, key, nullptr, nullptr, nullptr, v);

  scores_kernel<<<dim3(4, NSPLIT, NBATCH), 256, 0, stream>>>(qry, key, part);
  softmax_kernel<<<dim3(CH, NBATCH), 64, 0, stream>>>(part, attn);

  mega_kernel<<<dim3(144, NBATCH), 512, 0, stream>>>(
      attn, valt, wo1_b, bo1, wo2_b, bo2, bng, bnb, bnm, bnv, (float*)d_out);
}